// Round 4
// baseline (254.493 us; speedup 1.0000x reference)
//
#include <hip/hip_runtime.h>
#include <hip/hip_cooperative_groups.h>

namespace cg = cooperative_groups;

#define NB 4
#define LL 8192
#define DD 1024
#define CHUNK 64
#define NT (LL / CHUNK)      // 128 tiles per batch
#define NF (NB * NT)         // 512 tiles total
#define NBLK 256             // cooperative grid: 1 block/CU
#define EPSV 1e-4f

// Single-kernel fused scan:
//   Phase A: per-tile local affine aggregates (each block owns 2 tiles)
//   Phase B: block-parallel scan of tile aggregates -> per-tile carry
//   Phase C: final scan seeded with carry (idx/p persist in LDS across syncs)
__global__ __launch_bounds__(1024) void k_fused(
    const float* __restrict__ hid, const void* __restrict__ mask_raw,
    const float* __restrict__ bprob, float* __restrict__ A,
    float* __restrict__ Bvec, float* __restrict__ carry,
    float* __restrict__ out) {
    cg::grid_group grid = cg::this_grid();
    const int tid = threadIdx.x;
    const int blk = blockIdx.x;
    const int lane = tid & 63, wv = tid >> 6;   // 16 waves

    __shared__ int   s_viol;
    __shared__ int   s_wsum[16];
    __shared__ int   s_idx[2][CHUNK];
    __shared__ float s_p[2][CHUNK];
    __shared__ float sa[1024];
    __shared__ float sb[1024];

    const int f0 = blk * 2;            // two adjacent tiles; pairs never straddle a batch
    const int b  = f0 >> 7;            // f = b*NT + t, NT = 128
    const int t0 = f0 & (NT - 1);
    const int l0 = t0 * CHUNK;

    // ---- mask dtype detect: int32 little-endian [0/1,0,0,0] vs uint8 (first 4 KB)
    if (tid == 0) s_viol = 0;
    __syncthreads();
    {
        unsigned int w = ((const unsigned int*)mask_raw)[tid];
        if ((w & 0xFFFFFF00u) != 0u || (w & 0xFFu) > 1u) atomicOr(&s_viol, 1);
    }
    __syncthreads();
    const bool is_int = (s_viol == 0);

    // ---- full-batch mask scan (redundant per block; mask is L2-resident)
    const int base = b * LL + tid * 8;
    int m[8];
    if (is_int) {
        const int* mi = (const int*)mask_raw;
        #pragma unroll
        for (int k = 0; k < 8; ++k) m[k] = mi[base + k];
    } else {
        const unsigned char* mb = (const unsigned char*)mask_raw;
        #pragma unroll
        for (int k = 0; k < 8; ++k) m[k] = (int)mb[base + k];
    }
    int c[8];
    int s = 0;
    #pragma unroll
    for (int k = 0; k < 8; ++k) { s += m[k]; c[k] = s; }
    int v = s;
    #pragma unroll
    for (int off = 1; off < 64; off <<= 1) {
        int u = __shfl_up(v, off, 64);
        if (lane >= off) v += u;
    }
    if (lane == 63) s_wsum[wv] = v;
    __syncthreads();
    if (wv == 0) {
        int w = (lane < 16) ? s_wsum[lane] : 0;
        #pragma unroll
        for (int off = 1; off < 16; off <<= 1) {
            int u = __shfl_up(w, off, 64);
            if (lane >= off) w += u;
        }
        if (lane < 16) s_wsum[lane] = w;
    }
    __syncthreads();
    const int excl = ((wv > 0) ? s_wsum[wv - 1] : 0) + (v - s);
    // keep only the 128 positions this block owns
    #pragma unroll
    for (int k = 0; k < 8; ++k) {
        int l = tid * 8 + k;
        int rel = l - l0;
        if (rel >= 0 && rel < 2 * CHUNK) s_idx[rel >> 6][rel & 63] = excl + c[k] - 1;
    }
    if (tid < 2 * CHUNK) {
        int l = l0 + tid;
        float pv = bprob[((size_t)(b * LL + l)) * 2 + 1];
        pv = fminf(fmaxf(pv, EPSV), 1.0f - EPSV);
        if (l == 0) pv = 1.0f;
        s_p[tid >> 6][tid & 63] = pv;
    }
    __syncthreads();

    // ---- Phase A: local scans (seed 0) -> tile aggregates
    const float* hb = hid + (size_t)b * LL * DD + tid;
    #pragma unroll
    for (int u = 0; u < 2; ++u) {
        float prev = 0.f, cumA = 1.f;
        #pragma unroll 4
        for (int t = 0; t < CHUNK; ++t) {
            float p = s_p[u][t];
            float x = hb[(size_t)s_idx[u][t] * DD];
            prev = fmaf(p, x, (1.f - p) * prev);
            cumA *= (1.f - p);
        }
        Bvec[(size_t)(f0 + u) * DD + tid] = prev;
        if (tid == 0) A[f0 + u] = cumA;
    }

    __threadfence();
    grid.sync();

    // ---- Phase B: affine scan over tiles; 512 (batch,d-slice-of-8) units, 2 per block
    #pragma unroll
    for (int uu = 0; uu < 2; ++uu) {
        const int bi  = blk * 2 + uu;
        const int bb  = bi / (DD / 8);
        const int ds0 = (bi % (DD / 8)) * 8;
        const int tile = tid >> 3;
        const int d    = ds0 + (tid & 7);
        sa[tid] = A[bb * NT + tile];
        sb[tid] = Bvec[(size_t)(bb * NT + tile) * DD + d];
        __syncthreads();
        #pragma unroll
        for (int off = 8; off < 1024; off <<= 1) {   // off in tid units = tile_off*8
            float pa = 1.f, pb = 0.f;
            const bool has = (tid >= off);
            if (has) { pa = sa[tid - off]; pb = sb[tid - off]; }
            __syncthreads();
            if (has) {
                float ca = sa[tid], cb = sb[tid];
                sa[tid] = pa * ca;
                sb[tid] = fmaf(ca, pb, cb);
            }
            __syncthreads();
        }
        const float ex = (tile == 0) ? 0.f : sb[tid - 8];
        carry[(size_t)(bb * NT + tile) * DD + d] = ex;
        __syncthreads();
    }

    __threadfence();
    grid.sync();

    // ---- Phase C: final scan seeded with carry; x re-read is L3-resident
    #pragma unroll
    for (int u = 0; u < 2; ++u) {
        float y = carry[(size_t)(f0 + u) * DD + tid];
        float* ob = out + ((size_t)b * LL + l0 + u * CHUNK) * DD + tid;
        #pragma unroll 4
        for (int t = 0; t < CHUNK; ++t) {
            float p = s_p[u][t];
            float x = hb[(size_t)s_idx[u][t] * DD];
            y = fmaf(p, x, (1.f - p) * y);
            ob[(size_t)t * DD] = y;
        }
    }
}

extern "C" void kernel_launch(void* const* d_in, const int* in_sizes, int n_in,
                              void* d_out, int out_size, void* d_ws, size_t ws_size,
                              hipStream_t stream) {
    const float* hid   = (const float*)d_in[0];
    const void*  mask  = d_in[1];
    const float* bprob = (const float*)d_in[2];
    float* out = (float*)d_out;

    char* ws = (char*)d_ws;
    float* A     = (float*)(ws);                       //   2 KB
    float* Bvec  = (float*)(ws + 4096);                //   2 MB
    float* carry = (float*)(ws + 4096 + 2097152);      //   2 MB

    void* args[] = {(void*)&hid, (void*)&mask, (void*)&bprob,
                    (void*)&A, (void*)&Bvec, (void*)&carry, (void*)&out};
    hipLaunchCooperativeKernel((const void*)k_fused, dim3(NBLK), dim3(1024),
                               args, 0, stream);
}

// Round 5
// 67.157 us; speedup vs baseline: 3.7895x; 3.7895x over previous
//
#include <hip/hip_runtime.h>

#define NB 4
#define LL 8192
#define DD 1024
#define CHUNK 32
#define NT (LL / CHUNK)   // 256 tiles per batch
#define EPSV 1e-4f

typedef float vf4 __attribute__((ext_vector_type(4)));

// ---------------- K1: mask dtype detect + cumsum idx + clipped p ----------------
__global__ __launch_bounds__(1024) void k_prep(const void* __restrict__ mask_raw,
                                               const float* __restrict__ bprob,
                                               int* __restrict__ idx,
                                               float* __restrict__ p_out) {
    const int b = blockIdx.x;
    const int tid = threadIdx.x;
    const int lane = tid & 63, wv = tid >> 6;   // 16 waves
    __shared__ int s_viol;
    __shared__ int s_wsum[16];
    if (tid == 0) s_viol = 0;
    __syncthreads();
    // Detect mask storage: int32 little-endian [0/1,0,0,0] vs uint8 (check 4 KB).
    {
        unsigned int w = ((const unsigned int*)mask_raw)[tid];
        if ((w & 0xFFFFFF00u) != 0u || (w & 0xFFu) > 1u) atomicOr(&s_viol, 1);
    }
    __syncthreads();
    const bool is_int = (s_viol == 0);

    const int base = b * LL + tid * 8;
    int m[8];
    if (is_int) {
        const int* mi = (const int*)mask_raw;
        #pragma unroll
        for (int k = 0; k < 8; ++k) m[k] = mi[base + k];
    } else {
        const unsigned char* mb = (const unsigned char*)mask_raw;
        #pragma unroll
        for (int k = 0; k < 8; ++k) m[k] = (int)mb[base + k];
    }
    int c[8];
    int s = 0;
    #pragma unroll
    for (int k = 0; k < 8; ++k) { s += m[k]; c[k] = s; }

    int v = s;
    #pragma unroll
    for (int off = 1; off < 64; off <<= 1) {
        int u = __shfl_up(v, off, 64);
        if (lane >= off) v += u;
    }
    if (lane == 63) s_wsum[wv] = v;
    __syncthreads();
    if (wv == 0) {
        int w = (lane < 16) ? s_wsum[lane] : 0;
        #pragma unroll
        for (int off = 1; off < 16; off <<= 1) {
            int u = __shfl_up(w, off, 64);
            if (lane >= off) w += u;
        }
        if (lane < 16) s_wsum[lane] = w;
    }
    __syncthreads();
    const int excl = ((wv > 0) ? s_wsum[wv - 1] : 0) + (v - s);
    #pragma unroll
    for (int k = 0; k < 8; ++k) idx[base + k] = excl + c[k] - 1;

    const float2* bp2 = (const float2*)bprob + (size_t)b * LL + tid * 8;
    #pragma unroll
    for (int k = 0; k < 8; ++k) {
        int l = tid * 8 + k;
        float pv = bp2[k].y;
        pv = fminf(fmaxf(pv, EPSV), 1.0f - EPSV);
        if (l == 0) pv = 1.0f;
        p_out[b * LL + l] = pv;
    }
}

// ---------------- K2: per-tile affine aggregate, float4 over d ----------------------
__global__ __launch_bounds__(256) void k_tile_agg(const float* __restrict__ hid,
                                                  const int* __restrict__ idx,
                                                  const float* __restrict__ p_ws,
                                                  float* __restrict__ A,
                                                  float* __restrict__ Bvec) {
    const int blk = blockIdx.x;            // b*NT + tile
    const int b = blk >> 8;                // NT = 256
    const int tile = blk & (NT - 1);
    const int dt = threadIdx.x;            // 256 threads, 4 floats each
    __shared__ int s_idx[CHUNK];
    __shared__ float s_p[CHUNK];
    const int l0 = tile * CHUNK;
    if (dt < CHUNK) {
        s_idx[dt] = idx[b * LL + l0 + dt];
        s_p[dt]  = p_ws[b * LL + l0 + dt];
    }
    __syncthreads();
    const vf4* hb = (const vf4*)(hid + (size_t)b * LL * DD) + dt;
    vf4 prev = {0.f, 0.f, 0.f, 0.f};
    float cumA = 1.f;
    #pragma unroll 8
    for (int t = 0; t < CHUNK; ++t) {
        const float p = s_p[t];
        const float a = 1.f - p;
        const vf4 x = hb[(size_t)s_idx[t] * (DD / 4)];
        prev = p * x + a * prev;
        cumA *= a;
    }
    ((vf4*)Bvec)[(size_t)blk * (DD / 4) + dt] = prev;
    if (dt == 0) A[blk] = cumA;
}

// ---------------- K3: block-parallel affine scan over 256 tiles -> exclusive carry --
__global__ __launch_bounds__(1024) void k_carry(const float* __restrict__ A,
                                                const float* __restrict__ Bvec,
                                                float* __restrict__ carry) {
    const int bi = blockIdx.x;                 // NB * (DD/4) = 1024 blocks
    const int b = bi >> 8;                     // DD/4 = 256
    const int ds0 = (bi & 255) * 4;
    const int tid = threadIdx.x;               // tile = tid>>2, dl = tid&3
    const int tile = tid >> 2;
    const int d = ds0 + (tid & 3);
    __shared__ float sa[1024], sb[1024];

    sa[tid] = A[b * NT + tile];
    sb[tid] = Bvec[(size_t)(b * NT + tile) * DD + d];
    __syncthreads();
    #pragma unroll
    for (int off = 4; off < 1024; off <<= 1) {     // off in tid units = tile_off*4
        float pa = 1.f, pb = 0.f;
        const bool has = (tid >= off);
        if (has) { pa = sa[tid - off]; pb = sb[tid - off]; }
        __syncthreads();
        if (has) {
            float ca = sa[tid], cb = sb[tid];
            sa[tid] = pa * ca;
            sb[tid] = fmaf(ca, pb, cb);
        }
        __syncthreads();
    }
    const float ex = (tile == 0) ? 0.f : sb[tid - 4];
    carry[(size_t)(b * NT + tile) * DD + d] = ex;
}

// ---------------- K4: final scan seeded with carry, float4 + nontemporal stores -----
__global__ __launch_bounds__(256) void k_final(const float* __restrict__ hid,
                                               const int* __restrict__ idx,
                                               const float* __restrict__ p_ws,
                                               const float* __restrict__ carry,
                                               float* __restrict__ out) {
    const int blk = blockIdx.x;
    const int b = blk >> 8;
    const int tile = blk & (NT - 1);
    const int dt = threadIdx.x;
    __shared__ int s_idx[CHUNK];
    __shared__ float s_p[CHUNK];
    const int l0 = tile * CHUNK;
    if (dt < CHUNK) {
        s_idx[dt] = idx[b * LL + l0 + dt];
        s_p[dt]  = p_ws[b * LL + l0 + dt];
    }
    __syncthreads();
    const vf4* hb = (const vf4*)(hid + (size_t)b * LL * DD) + dt;
    vf4 y = ((const vf4*)carry)[(size_t)blk * (DD / 4) + dt];
    vf4* ob = (vf4*)(out + ((size_t)b * LL + l0) * DD) + dt;
    #pragma unroll 8
    for (int t = 0; t < CHUNK; ++t) {
        const float p = s_p[t];
        const float a = 1.f - p;
        const vf4 x = hb[(size_t)s_idx[t] * (DD / 4)];
        y = p * x + a * y;
        __builtin_nontemporal_store(y, &ob[(size_t)t * (DD / 4)]);
    }
}

extern "C" void kernel_launch(void* const* d_in, const int* in_sizes, int n_in,
                              void* d_out, int out_size, void* d_ws, size_t ws_size,
                              hipStream_t stream) {
    const float* hid   = (const float*)d_in[0];
    const void*  mask  = d_in[1];
    const float* bprob = (const float*)d_in[2];
    float* out = (float*)d_out;

    char* ws = (char*)d_ws;
    int*   idx   = (int*)(ws);                                   // 128 KB
    float* p_ws  = (float*)(ws + 131072);                        // 128 KB
    float* A     = (float*)(ws + 262144);                        //   4 KB
    float* Bvec  = (float*)(ws + 266240);                        //   4 MB
    float* carry = (float*)(ws + 266240 + 4194304);              //   4 MB

    k_prep<<<NB, 1024, 0, stream>>>(mask, bprob, idx, p_ws);
    k_tile_agg<<<NB * NT, 256, 0, stream>>>(hid, idx, p_ws, A, Bvec);
    k_carry<<<NB * (DD / 4), 1024, 0, stream>>>(A, Bvec, carry);
    k_final<<<NB * NT, 256, 0, stream>>>(hid, idx, p_ws, carry, out);
}

// Round 6
// 55.760 us; speedup vs baseline: 4.5641x; 1.2044x over previous
//
#include <hip/hip_runtime.h>

#define NB 4
#define LL 8192
#define DD 1024
#define CHUNK 64
#define NT (LL / CHUNK)   // 128 tiles per batch
#define EPSV 1e-4f

typedef float vf4 __attribute__((ext_vector_type(4)));

// ---------------- K1: fused prep + per-tile weighted-row aggregate ----------------
// Each block: (batch, tile of 64 positions). Redundantly scans its batch's mask
// (L2-resident), derives idx/p for its tile, computes per-distinct-row weights
// w_r from p alone, then B_tile = sum_r w_r * x_r  (independent FMAs, ~32 rows).
__global__ __launch_bounds__(256) void k_agg(const float* __restrict__ hid,
                                             const void* __restrict__ mask_raw,
                                             const float* __restrict__ bprob,
                                             int* __restrict__ idx_g,
                                             float* __restrict__ p_g,
                                             float* __restrict__ A,
                                             float* __restrict__ Bvec) {
    const int blk = blockIdx.x;            // b*NT + tile
    const int b = blk >> 7;                // NT = 128
    const int tile = blk & (NT - 1);
    const int l0 = tile * CHUNK;
    const int tid = threadIdx.x;           // 256 threads
    const int lane = tid & 63, wv = tid >> 6;

    __shared__ int   s_viol;
    __shared__ int   s_wsum[4];
    __shared__ int   s_idx[CHUNK];
    __shared__ float s_p[CHUNK];
    __shared__ float s_w[CHUNK];
    __shared__ float s_cumA;

    // mask dtype detect: int32 little-endian [0/1,0,0,0] vs uint8 (first 1 KB)
    if (tid == 0) s_viol = 0;
    __syncthreads();
    {
        unsigned int w = ((const unsigned int*)mask_raw)[tid];
        if ((w & 0xFFFFFF00u) != 0u || (w & 0xFFu) > 1u) atomicOr(&s_viol, 1);
    }
    __syncthreads();
    const bool is_int = (s_viol == 0);

    // full-batch mask scan: 256 threads x 32 elements each
    const int e0 = b * LL + tid * 32;
    int s = 0;
    if (is_int) {
        const int4* mi = (const int4*)((const int*)mask_raw + e0);
        #pragma unroll
        for (int k = 0; k < 8; ++k) { int4 q = mi[k]; s += q.x + q.y + q.z + q.w; }
    } else {
        const unsigned int* mb = (const unsigned int*)((const unsigned char*)mask_raw + e0);
        #pragma unroll
        for (int k = 0; k < 8; ++k) s += (int)((mb[k] * 0x01010101u) >> 24);
    }
    int v = s;
    #pragma unroll
    for (int off = 1; off < 64; off <<= 1) {
        int u = __shfl_up(v, off, 64);
        if (lane >= off) v += u;
    }
    if (lane == 63) s_wsum[wv] = v;
    __syncthreads();
    int wexcl = 0;
    #pragma unroll
    for (int i = 0; i < 4; ++i) if (i < wv) wexcl += s_wsum[i];
    const int excl = wexcl + (v - s);      // exclusive prefix for this thread's range

    // the two threads whose 32-elem ranges cover [l0, l0+64) emit idx
    if ((tid >> 1) == (l0 >> 6)) {         // tid == l0/32 or l0/32+1
        int run = excl;
        if (is_int) {
            const int* mi = (const int*)mask_raw + e0;
            for (int k = 0; k < 32; ++k) { run += mi[k]; s_idx[tid * 32 + k - l0] = run - 1; }
        } else {
            const unsigned char* mb = (const unsigned char*)mask_raw + e0;
            for (int k = 0; k < 32; ++k) { run += mb[k]; s_idx[tid * 32 + k - l0] = run - 1; }
        }
    }
    if (tid < CHUNK) {
        const int l = l0 + tid;
        float pv = bprob[((size_t)(b * LL + l)) * 2 + 1];
        pv = fminf(fmaxf(pv, EPSV), 1.0f - EPSV);
        if (l == 0) pv = 1.0f;
        s_p[tid] = pv;
        s_w[tid] = 0.f;
    }
    __syncthreads();

    // wave 0: suffix products -> per-row weights
    if (wv == 0) {
        const float a = 1.f - s_p[lane];
        float P = a;                               // inclusive suffix product
        #pragma unroll
        for (int off = 1; off < 64; off <<= 1) {
            float u = __shfl_down(P, off, 64);
            if (lane < 64 - off) P *= u;
        }
        float S = __shfl_down(P, 1, 64);           // exclusive suffix product
        if (lane == 63) S = 1.f;
        atomicAdd(&s_w[s_idx[lane] - s_idx[0]], S * s_p[lane]);
        if (lane == 0) s_cumA = P;
    }
    __syncthreads();

    // weighted gather: independent FMAs over ~nrow distinct rows
    const int r0 = s_idx[0];
    const int nrow = s_idx[CHUNK - 1] - r0 + 1;
    const vf4* hb = (const vf4*)(hid + (size_t)b * LL * DD) + (size_t)r0 * (DD / 4) + tid;
    vf4 acc = {0.f, 0.f, 0.f, 0.f};
    #pragma unroll 4
    for (int r = 0; r < nrow; ++r)
        acc += s_w[r] * hb[(size_t)r * (DD / 4)];
    ((vf4*)Bvec)[(size_t)blk * (DD / 4) + tid] = acc;
    if (tid == 0) A[blk] = s_cumA;
    if (tid < CHUNK) {
        idx_g[b * LL + l0 + tid] = s_idx[tid];
        p_g[b * LL + l0 + tid]  = s_p[tid];
    }
}

// ---------------- K2: block-parallel affine scan over tiles -> exclusive carry ------
// One block = one batch x 8 d-channels; threads = 128 tiles x 8 d; 7 LDS scan steps.
__global__ __launch_bounds__(1024) void k_carry(const float* __restrict__ A,
                                                const float* __restrict__ Bvec,
                                                float* __restrict__ carry) {
    const int bi = blockIdx.x;                 // NB * (DD/8) = 512 blocks
    const int b = bi / (DD / 8);
    const int ds0 = (bi % (DD / 8)) * 8;
    const int tid = threadIdx.x;
    const int tile = tid >> 3;
    const int d = ds0 + (tid & 7);
    __shared__ float sa[1024], sb[1024];

    sa[tid] = A[b * NT + tile];
    sb[tid] = Bvec[(size_t)(b * NT + tile) * DD + d];
    __syncthreads();
    #pragma unroll
    for (int off = 8; off < 1024; off <<= 1) {     // off in tid units = tile_off*8
        float pa = 1.f, pb = 0.f;
        const bool has = (tid >= off);
        if (has) { pa = sa[tid - off]; pb = sb[tid - off]; }
        __syncthreads();
        if (has) {
            float ca = sa[tid], cb = sb[tid];
            sa[tid] = pa * ca;
            sb[tid] = fmaf(ca, pb, cb);
        }
        __syncthreads();
    }
    const float ex = (tile == 0) ? 0.f : sb[tid - 8];
    carry[(size_t)(b * NT + tile) * DD + d] = ex;
}

// ---------------- K3: final scan seeded with carry, nontemporal stores --------------
__global__ __launch_bounds__(1024) void k_final(const float* __restrict__ hid,
                                                const int* __restrict__ idx,
                                                const float* __restrict__ p_ws,
                                                const float* __restrict__ carry,
                                                float* __restrict__ out) {
    const int blk = blockIdx.x;
    const int b = blk >> 7;
    const int tile = blk & (NT - 1);
    const int d = threadIdx.x;
    __shared__ int s_idx[CHUNK];
    __shared__ float s_p[CHUNK];
    const int l0 = tile * CHUNK;
    if (d < CHUNK) {
        s_idx[d] = idx[b * LL + l0 + d];
        s_p[d]  = p_ws[b * LL + l0 + d];
    }
    __syncthreads();
    float y = carry[(size_t)blk * DD + d];
    const float* hb = hid + (size_t)b * LL * DD + d;
    float* ob = out + ((size_t)b * LL + l0) * DD + d;
    #pragma unroll 8
    for (int t = 0; t < CHUNK; ++t) {
        const float p = s_p[t];
        const float x = hb[(size_t)s_idx[t] * DD];
        y = fmaf(p, x, (1.f - p) * y);
        __builtin_nontemporal_store(y, &ob[(size_t)t * DD]);
    }
}

extern "C" void kernel_launch(void* const* d_in, const int* in_sizes, int n_in,
                              void* d_out, int out_size, void* d_ws, size_t ws_size,
                              hipStream_t stream) {
    const float* hid   = (const float*)d_in[0];
    const void*  mask  = d_in[1];
    const float* bprob = (const float*)d_in[2];
    float* out = (float*)d_out;

    char* ws = (char*)d_ws;
    int*   idx   = (int*)(ws);                                   // 128 KB
    float* p_ws  = (float*)(ws + 131072);                        // 128 KB
    float* A     = (float*)(ws + 262144);                        //   2 KB
    float* Bvec  = (float*)(ws + 264192);                        //   2 MB
    float* carry = (float*)(ws + 264192 + 2097152);              //   2 MB

    k_agg<<<NB * NT, 256, 0, stream>>>(hid, mask, bprob, idx, p_ws, A, Bvec);
    k_carry<<<NB * (DD / 8), 1024, 0, stream>>>(A, Bvec, carry);
    k_final<<<NB * NT, 1024, 0, stream>>>(hid, idx, p_ws, carry, out);
}

// Round 7
// 51.574 us; speedup vs baseline: 4.9345x; 1.0812x over previous
//
#include <hip/hip_runtime.h>

#define NB 4
#define LL 8192
#define DD 1024
#define CHUNK 64
#define NT (LL / CHUNK)   // 128 tiles per batch
#define EPSV 1e-4f

typedef float vf4 __attribute__((ext_vector_type(4)));

// ---------------- K1: fused prep + per-tile weighted-row aggregate ----------------
// Each block: (batch, tile of 64 positions). Redundantly scans its batch's mask
// (L2-resident) for the tile's base chunk-index, then ONE wave derives idx,
// per-row weights w_r (suffix products of a=1-p), and cumA. Tile aggregate
// B = sum_r w_r * x_r : independent float4 FMAs over ~32 distinct rows.
__global__ __launch_bounds__(256) void k_agg(const float* __restrict__ hid,
                                             const void* __restrict__ mask_raw,
                                             const float* __restrict__ bprob,
                                             int* __restrict__ idx_g,
                                             float* __restrict__ p_g,
                                             float* __restrict__ A,
                                             float* __restrict__ Bvec) {
    const int blk = blockIdx.x;            // b*NT + tile
    const int b = blk >> 7;                // NT = 128
    const int tile = blk & (NT - 1);
    const int l0 = tile * CHUNK;
    const int tid = threadIdx.x;           // 256 threads
    const int lane = tid & 63, wv = tid >> 6;

    __shared__ int   s_viol;
    __shared__ int   s_wsum[4];
    __shared__ int   s_base;
    __shared__ int   s_idx[CHUNK];
    __shared__ float s_p[CHUNK];
    __shared__ float s_w[CHUNK];
    __shared__ float s_cumA;

    // mask dtype detect: int32 little-endian [0/1,0,0,0] vs uint8 (first 1 KB)
    if (tid == 0) s_viol = 0;
    __syncthreads();
    {
        unsigned int w = ((const unsigned int*)mask_raw)[tid];
        if ((w & 0xFFFFFF00u) != 0u || (w & 0xFFu) > 1u) atomicOr(&s_viol, 1);
    }
    __syncthreads();
    const bool is_int = (s_viol == 0);

    // full-batch mask reduction: 256 threads x 32 elems -> exclusive prefix at l0
    const int e0 = b * LL + tid * 32;
    int s = 0;
    if (is_int) {
        const int4* mi = (const int4*)((const int*)mask_raw + e0);
        #pragma unroll
        for (int k = 0; k < 8; ++k) { int4 q = mi[k]; s += q.x + q.y + q.z + q.w; }
    } else {
        const unsigned int* mb = (const unsigned int*)((const unsigned char*)mask_raw + e0);
        #pragma unroll
        for (int k = 0; k < 8; ++k) s += (int)((mb[k] * 0x01010101u) >> 24);
    }
    int v = s;
    #pragma unroll
    for (int off = 1; off < 64; off <<= 1) {
        int u = __shfl_up(v, off, 64);
        if (lane >= off) v += u;
    }
    if (lane == 63) s_wsum[wv] = v;
    __syncthreads();
    int wexcl = 0;
    #pragma unroll
    for (int i = 0; i < 4; ++i) if (i < wv) wexcl += s_wsum[i];
    const int excl = wexcl + (v - s);      // #boundaries before this thread's range
    if (tid == tile * 2) s_base = excl;    // thread whose range starts at l0

    if (tid < CHUNK) {
        const int l = l0 + tid;
        float pv = bprob[((size_t)(b * LL + l)) * 2 + 1];
        pv = fminf(fmaxf(pv, EPSV), 1.0f - EPSV);
        if (l == 0) pv = 1.0f;
        s_p[tid] = pv;
        s_w[tid] = 0.f;
    }
    __syncthreads();

    // wave 0 (64 lanes == 64 positions): idx scan + suffix-product weights
    if (wv == 0) {
        int mval;
        if (is_int) mval = ((const int*)mask_raw)[b * LL + l0 + lane];
        else        mval = (int)((const unsigned char*)mask_raw)[b * LL + l0 + lane];
        int c = mval;
        #pragma unroll
        for (int off = 1; off < 64; off <<= 1) {
            int u = __shfl_up(c, off, 64);
            if (lane >= off) c += u;
        }
        const int my_idx = s_base + c - 1;
        s_idx[lane] = my_idx;
        const int r0 = __shfl(my_idx, 0, 64);

        const float a = 1.f - s_p[lane];
        float P = a;                               // inclusive suffix product
        #pragma unroll
        for (int off = 1; off < 64; off <<= 1) {
            float u = __shfl_down(P, off, 64);
            if (lane < 64 - off) P *= u;
        }
        float S = __shfl_down(P, 1, 64);           // exclusive suffix product
        if (lane == 63) S = 1.f;
        atomicAdd(&s_w[my_idx - r0], S * s_p[lane]);
        if (lane == 0) s_cumA = P;
    }
    __syncthreads();

    // weighted gather: independent float4 FMAs over nrow distinct rows
    const int r0 = s_idx[0];
    const int nrow = s_idx[CHUNK - 1] - r0 + 1;
    const vf4* hb = (const vf4*)(hid + (size_t)b * LL * DD) + (size_t)r0 * (DD / 4) + tid;
    vf4 acc = {0.f, 0.f, 0.f, 0.f};
    #pragma unroll 4
    for (int r = 0; r < nrow; ++r)
        acc += s_w[r] * hb[(size_t)r * (DD / 4)];
    ((vf4*)Bvec)[(size_t)blk * (DD / 4) + tid] = acc;
    if (tid == 0) A[blk] = s_cumA;
    if (tid < CHUNK) {
        idx_g[b * LL + l0 + tid] = s_idx[tid];
        p_g[b * LL + l0 + tid]  = s_p[tid];
    }
}

// ---------------- K2: fused carry + final scan --------------------------------------
// Each block (b,T) recomputes its own exclusive carry from the tile aggregates:
//   carry = sum_{j<T} W_j * Bvec[j],  W_j = prod_{k=j+1}^{T-1} A_k  (exact, via
// 7-step LDS suffix-product scan). Terms with W_j < 1e-7 are skipped — bound on
// skipped contribution: 128 * max|Bvec| * 1e-7 ~ 6e-5, far under threshold. With
// random p the sum is 1-2 terms; adversarial data degrades to the full 127-term
// sum and stays correct. Then the tile's output scan, seeded with carry.
__global__ __launch_bounds__(1024) void k_fin(const float* __restrict__ hid,
                                              const int* __restrict__ idx,
                                              const float* __restrict__ p_ws,
                                              const float* __restrict__ A,
                                              const float* __restrict__ Bvec,
                                              float* __restrict__ out) {
    const int blk = blockIdx.x;
    const int b = blk >> 7;
    const int T = blk & (NT - 1);
    const int tid = threadIdx.x;
    const int l0 = T * CHUNK;

    __shared__ float s_P[NT];      // s_P[j] = prod_{k=j}^{T-1} A_k (1 for j>=T)
    __shared__ int   s_idx[CHUNK];
    __shared__ float s_p[CHUNK];
    __shared__ int   s_jmin;

    if (tid < CHUNK) {
        s_idx[tid] = idx[b * LL + l0 + tid];
        s_p[tid]  = p_ws[b * LL + l0 + tid];
    }
    if (tid == 128) s_jmin = T;
    if (tid < NT) s_P[tid] = (tid < T) ? A[b * NT + tid] : 1.f;
    __syncthreads();
    #pragma unroll
    for (int off = 1; off < NT; off <<= 1) {
        float self = 1.f, other = 1.f;
        if (tid < NT) { self = s_P[tid]; if (tid + off < NT) other = s_P[tid + off]; }
        __syncthreads();
        if (tid < NT) s_P[tid] = self * other;
        __syncthreads();
    }
    if (tid < T) {
        if (s_P[tid + 1] > 1e-7f) atomicMin(&s_jmin, tid);   // W_tid = s_P[tid+1]
    }
    __syncthreads();

    float carry = 0.f;
    const int jmin = s_jmin;
    for (int j = jmin; j < T; ++j)
        carry = fmaf(s_P[j + 1], Bvec[((size_t)(b * NT + j)) * DD + tid], carry);

    const float* hb = hid + (size_t)b * LL * DD + tid;
    float* ob = out + ((size_t)b * LL + l0) * DD + tid;
    float y = carry;
    #pragma unroll 8
    for (int t = 0; t < CHUNK; ++t) {
        const float p = s_p[t];
        const float x = hb[(size_t)s_idx[t] * DD];
        y = fmaf(p, x, (1.f - p) * y);
        __builtin_nontemporal_store(y, &ob[(size_t)t * DD]);
    }
}

extern "C" void kernel_launch(void* const* d_in, const int* in_sizes, int n_in,
                              void* d_out, int out_size, void* d_ws, size_t ws_size,
                              hipStream_t stream) {
    const float* hid   = (const float*)d_in[0];
    const void*  mask  = d_in[1];
    const float* bprob = (const float*)d_in[2];
    float* out = (float*)d_out;

    char* ws = (char*)d_ws;
    int*   idx   = (int*)(ws);                                   // 128 KB
    float* p_ws  = (float*)(ws + 131072);                        // 128 KB
    float* A     = (float*)(ws + 262144);                        //   2 KB
    float* Bvec  = (float*)(ws + 264192);                        //   2 MB

    k_agg<<<NB * NT, 256, 0, stream>>>(hid, mask, bprob, idx, p_ws, A, Bvec);
    k_fin<<<NB * NT, 1024, 0, stream>>>(hid, idx, p_ws, A, Bvec, out);
}